// Round 16
// baseline (121.229 us; speedup 1.0000x reference)
//
#include <hip/hip_runtime.h>
#include <hip/hip_bf16.h>
#include <cstdint>
#include <cstddef>

// ---------- types ----------
using bf16x8 = __attribute__((ext_vector_type(8))) short;
using f32x4  = __attribute__((ext_vector_type(4))) float;

#define MFMA16(a, b, c) __builtin_amdgcn_mfma_f32_16x16x32_bf16((a), (b), (c), 0, 0, 0)

__device__ __forceinline__ unsigned short f2bf(float f) {
    unsigned int u = __float_as_uint(f);
    u += 0x7fffu + ((u >> 16) & 1u);   // round-to-nearest-even
    return (unsigned short)(u >> 16);
}
__device__ __forceinline__ uint32_t pack2bf(float a, float b) {
    __hip_bfloat162 h = __float22bfloat162_rn(float2{a, b});
    return *(uint32_t*)&h;
}
__device__ __forceinline__ float bf2f(short x) {
    return __uint_as_float(((uint32_t)(unsigned short)x) << 16);
}

__device__ __forceinline__ void gload_lds16(const void* g, void* l) {
    __builtin_amdgcn_global_load_lds(
        (const __attribute__((address_space(1))) void*)g,
        (__attribute__((address_space(3))) void*)l, 16, 0, 0);
}

// ---------- constants ----------
#define S_LEN 2048
#define NHEAD 16
#define HDIM  64
#define DIM   1024
#define WIN   512
#define MROWS 4096            // B*S

// ---------- kernel 0 (fused prep): rope table + 3 bf16 casts ----------
__global__ void prep(float* __restrict__ cosT, float* __restrict__ sinT,
                     const float* __restrict__ x, unsigned short* __restrict__ xb,
                     const float* __restrict__ qw, unsigned short* __restrict__ qwb,
                     const float* __restrict__ ow, unsigned short* __restrict__ owb) {
    int t = blockIdx.x * 256 + threadIdx.x;
    if (t < 65536) {
        int s = t >> 5, f = t & 31;
        float invf = powf(10000.0f, -(float)f / 32.0f);
        float ang = (float)s * invf;
        cosT[t] = cosf(ang);
        sinT[t] = sinf(ang);
        return;
    }
    int u = t - 65536;
    const float* src;
    unsigned short* dst;
    int i;
    if (u < 1048576)        { src = x;  dst = xb;  i = u * 4; }
    else if (u < 1835008)   { src = qw; dst = qwb; i = (u - 1048576) * 4; }
    else                    { src = ow; dst = owb; i = (u - 1835008) * 4; }
    float4 v = *(const float4*)(src + i);
    ushort4 o;
    o.x = f2bf(v.x); o.y = f2bf(v.y); o.z = f2bf(v.z); o.w = f2bf(v.w);
    *(ushort4*)(dst + i) = o;
}

// ---------- fused QKV GEMM: 256x256 tile, 8-phase counted-vmcnt schedule (R11-proven) ----------
// Grid (16 by-fast, 12 bx): 16%8==0 -> all 12 blocks sharing an A-row-tile land on ONE XCD
// (A L2-resident; R14 counter-proof: FETCH 47.0 -> 35.5MB).
__global__ __launch_bounds__(512, 2) void gemm_qkv8(
        const unsigned short* __restrict__ A,    // xb   [4096][1024]
        const unsigned short* __restrict__ Bw,   // wqb  [3072][1024]
        const float* __restrict__ bias,          // qkv_b[3072]
        const float* __restrict__ cosT, const float* __restrict__ sinT,
        unsigned short* __restrict__ qbuf,       // [32][2048][64]
        unsigned short* __restrict__ kbuf,       // [32][2048][64]
        unsigned short* __restrict__ vtb) {      // [32][64][2048]
    __shared__ __align__(16) char smem[131072];
    const int tid = threadIdx.x;
    const int lane = tid & 63, w = tid >> 6;
    const int wr = w >> 2, wn = w & 3;           // M-half, N-quarter
    const int lm = lane & 15, lg = lane >> 4;
    const int bx = blockIdx.y, by = blockIdx.x;  // by = fast axis
    const int row0 = by * 256, col0 = bx * 256;

    f32x4 acc[8][4];
#pragma unroll
    for (int mf = 0; mf < 8; ++mf)
#pragma unroll
        for (int nf = 0; nf < 4; ++nf) acc[mf][nf] = (f32x4){0.f, 0.f, 0.f, 0.f};

    short* SA0 = (short*)smem;                   // buf0 A (32KB)
    short* SB0 = (short*)(smem + 32768);         // buf0 B
    short* SA1 = (short*)(smem + 65536);         // buf1 A
    short* SB1 = (short*)(smem + 98304);         // buf1 B

    auto stageA = [&](int t) {
        int tt = t & 15;                          // wrap keeps parity; dummies harmless
        short* dst = (tt & 1) ? SA1 : SA0;
#pragma unroll
        for (int j = 0; j < 4; ++j) {
            int slot = tid + 512 * j;             // 2048 x 16B = 32KB
            int r = slot >> 3, gp = slot & 7, gs = gp ^ (r & 7);
            gload_lds16((const char*)A + (size_t)(row0 + r) * 2048 + tt * 128 + gs * 16,
                        dst + slot * 8);
        }
    };
    auto stageB = [&](int t) {
        int tt = t & 15;
        short* dst = (tt & 1) ? SB1 : SB0;
#pragma unroll
        for (int j = 0; j < 4; ++j) {
            int slot = tid + 512 * j;
            int r = slot >> 3, gp = slot & 7, gs = gp ^ (r & 7);
            gload_lds16((const char*)Bw + (size_t)(col0 + r) * 2048 + tt * 128 + gs * 16,
                        dst + slot * 8);
        }
    };

    // prologue: A(0) B(0) B(1) -> 12 outstanding; Ph1's vmcnt(4) waits oldest 8 (t0 A+B)
    stageA(0); stageB(0); stageB(1);

    const int rA = wr * 128;                     // wave A-row base
    const int rB = wn * 64;                      // wave B-row base

    for (int i = 0; i < 8; ++i) {
        const int u = 2 * i, v = 2 * i + 1;
        bf16x8 a[8], bq[4][2];
        // ---- Ph1: read u(kh0 A, both-kh B) from buf0; stage A(v)->buf1A; MFMA u,kh0
        asm volatile("s_waitcnt vmcnt(4)" ::: "memory");
        __builtin_amdgcn_s_barrier();
#pragma unroll
        for (int mf = 0; mf < 8; ++mf) {
            int r = rA + mf * 16 + lm;
            a[mf] = *(const bf16x8*)&SA0[r * 64 + ((lg ^ (r & 7)) << 3)];
        }
#pragma unroll
        for (int nf = 0; nf < 4; ++nf) {
            int r = rB + nf * 16 + lm;
            bq[nf][0] = *(const bf16x8*)&SB0[r * 64 + ((lg ^ (r & 7)) << 3)];
            bq[nf][1] = *(const bf16x8*)&SB0[r * 64 + (((lg + 4) ^ (r & 7)) << 3)];
        }
        stageA(v);
        __builtin_amdgcn_s_setprio(1);
#pragma unroll
        for (int mf = 0; mf < 8; ++mf)
#pragma unroll
            for (int nf = 0; nf < 4; ++nf)
                acc[mf][nf] = MFMA16(a[mf], bq[nf][0], acc[mf][nf]);
        __builtin_amdgcn_s_setprio(0);
        // ---- Ph2: read u kh1 A; stage B(u+2)->buf0B; MFMA u,kh1
        __builtin_amdgcn_s_barrier();
#pragma unroll
        for (int mf = 0; mf < 8; ++mf) {
            int r = rA + mf * 16 + lm;
            a[mf] = *(const bf16x8*)&SA0[r * 64 + (((lg + 4) ^ (r & 7)) << 3)];
        }
        stageB(u + 2);
        __builtin_amdgcn_s_setprio(1);
#pragma unroll
        for (int mf = 0; mf < 8; ++mf)
#pragma unroll
            for (int nf = 0; nf < 4; ++nf)
                acc[mf][nf] = MFMA16(a[mf], bq[nf][1], acc[mf][nf]);
        __builtin_amdgcn_s_setprio(0);
        // ---- Ph3: read v(kh0 A, both-kh B) from buf1; stage A(u+2)->buf0A; MFMA v,kh0
        asm volatile("s_waitcnt vmcnt(4)" ::: "memory");
        __builtin_amdgcn_s_barrier();
#pragma unroll
        for (int mf = 0; mf < 8; ++mf) {
            int r = rA + mf * 16 + lm;
            a[mf] = *(const bf16x8*)&SA1[r * 64 + ((lg ^ (r & 7)) << 3)];
        }
#pragma unroll
        for (int nf = 0; nf < 4; ++nf) {
            int r = rB + nf * 16 + lm;
            bq[nf][0] = *(const bf16x8*)&SB1[r * 64 + ((lg ^ (r & 7)) << 3)];
            bq[nf][1] = *(const bf16x8*)&SB1[r * 64 + (((lg + 4) ^ (r & 7)) << 3)];
        }
        stageA(u + 2);
        __builtin_amdgcn_s_setprio(1);
#pragma unroll
        for (int mf = 0; mf < 8; ++mf)
#pragma unroll
            for (int nf = 0; nf < 4; ++nf)
                acc[mf][nf] = MFMA16(a[mf], bq[nf][0], acc[mf][nf]);
        __builtin_amdgcn_s_setprio(0);
        // ---- Ph4: read v kh1 A; stage B(v+2)->buf1B; MFMA v,kh1
        __builtin_amdgcn_s_barrier();
#pragma unroll
        for (int mf = 0; mf < 8; ++mf) {
            int r = rA + mf * 16 + lm;
            a[mf] = *(const bf16x8*)&SA1[r * 64 + (((lg + 4) ^ (r & 7)) << 3)];
        }
        stageB(v + 2);
        __builtin_amdgcn_s_setprio(1);
#pragma unroll
        for (int mf = 0; mf < 8; ++mf)
#pragma unroll
            for (int nf = 0; nf < 4; ++nf)
                acc[mf][nf] = MFMA16(a[mf], bq[nf][1], acc[mf][nf]);
        __builtin_amdgcn_s_setprio(0);
    }
    // drain dummy stages before LDS overlay reuse
    asm volatile("s_waitcnt vmcnt(0)" ::: "memory");
    __builtin_amdgcn_s_barrier();

    // ---------- fused epilogue: bias + (RoPE pack | V transpose), 2 passes of 128 rows ----------
    const int plane = bx >> 2;                   // 0=Q 1=K 2=V
    const int h0 = (bx & 3) * 4;                 // 4 heads per 256-col tile
    const int b = by >> 3, s_base = (by & 7) * 256;
    const int lane8 = tid & 7, idx = tid >> 3;   // idx 0..63

#pragma unroll 1
    for (int p = 0; p < 2; ++p) {
        if (plane < 2) {
            unsigned short (*tile)[264] = (unsigned short(*)[264])smem;  // [128][256+8]
            if (wr == p) {
#pragma unroll
                for (int mf = 0; mf < 8; ++mf)
#pragma unroll
                    for (int nf = 0; nf < 4; ++nf) {
                        int colL = wn * 64 + nf * 16 + lm;
                        float bv = bias[col0 + colL];
#pragma unroll
                        for (int r = 0; r < 4; ++r)
                            tile[mf * 16 + lg * 4 + r][colL] = f2bf(acc[mf][nf][r] + bv);
                    }
            }
            __syncthreads();
            unsigned short* dstp = (plane == 0) ? qbuf : kbuf;
            const float qsc = (plane == 0) ? 0.125f : 1.0f;
            int d0 = lane8 * 8;
#pragma unroll
            for (int j = 0; j < 2; ++j) {
                int rloc = idx + 64 * j;                     // 0..127
                int s = s_base + p * 128 + rloc;
                float4 c4 = *(const float4*)&cosT[s * 32 + (d0 >> 1)];
                float4 s4 = *(const float4*)&sinT[s * 32 + (d0 >> 1)];
#pragma unroll
                for (int hh = 0; hh < 4; ++hh) {
                    bf16x8 vld = *(const bf16x8*)&tile[rloc][hh * 64 + d0];
                    float e0 = bf2f(vld[0]), o0 = bf2f(vld[1]);
                    float e1 = bf2f(vld[2]), o1 = bf2f(vld[3]);
                    float e2 = bf2f(vld[4]), o2 = bf2f(vld[5]);
                    float e3 = bf2f(vld[6]), o3 = bf2f(vld[7]);
                    uint4 pk;
                    pk.x = pack2bf((e0 * c4.x - o0 * s4.x) * qsc, (e0 * s4.x + o0 * c4.x) * qsc);
                    pk.y = pack2bf((e1 * c4.y - o1 * s4.y) * qsc, (e1 * s4.y + o1 * c4.y) * qsc);
                    pk.z = pack2bf((e2 * c4.z - o2 * s4.z) * qsc, (e2 * s4.z + o2 * c4.z) * qsc);
                    pk.w = pack2bf((e3 * c4.w - o3 * s4.w) * qsc, (e3 * s4.w + o3 * c4.w) * qsc);
                    int h = h0 + hh;
                    *(uint4*)&dstp[(((size_t)(b * NHEAD + h)) * S_LEN + s) * 64 + d0] = pk;
                }
            }
            __syncthreads();
        } else {
            unsigned short (*tileT)[136] = (unsigned short(*)[136])smem;  // [256][128+8]
            if (wr == p) {
#pragma unroll
                for (int mf = 0; mf < 8; ++mf)
#pragma unroll
                    for (int nf = 0; nf < 4; ++nf) {
                        int colL = wn * 64 + nf * 16 + lm;
                        float bv = bias[col0 + colL];
                        uint2 pk;
                        pk.x = pack2bf(acc[mf][nf][0] + bv, acc[mf][nf][1] + bv);
                        pk.y = pack2bf(acc[mf][nf][2] + bv, acc[mf][nf][3] + bv);
                        *(uint2*)&tileT[colL][mf * 16 + lg * 4] = pk;
                    }
            }
            __syncthreads();
#pragma unroll
            for (int ff = 0; ff < 4; ++ff) {
                int f = ff * 64 + idx;                       // feature 0..255
                int hh = f >> 6, d = f & 63, h = h0 + hh;
#pragma unroll
                for (int j = 0; j < 2; ++j) {
                    int s0 = lane8 * 8 + j * 64;             // 0..127
                    bf16x8 vld = *(const bf16x8*)&tileT[f][s0];
                    *(bf16x8*)&vtb[((size_t)(b * NHEAD + h) * 64 + d) * S_LEN +
                                   s_base + p * 128 + s0] = vld;
                }
            }
            __syncthreads();
        }
    }
}

// ---------- out-proj GEMM: 128x64 tile, BK=64, single buffer, fp32 out ----------
__global__ __launch_bounds__(256) void gemm_out(const unsigned short* __restrict__ A,
                                                const unsigned short* __restrict__ Bw,
                                                const float* __restrict__ bias,
                                                float* __restrict__ Cout) {
    __shared__ __align__(16) char smem_raw[24576];  // A [128][64] 16KB + B [64][64] 8KB
    const int tid = threadIdx.x;
    const int lane = tid & 63, w = tid >> 6;
    const int wr = w >> 1, wc = w & 1, lm = lane & 15, lg = lane >> 4;
    const int row0 = blockIdx.y * 128, col0 = blockIdx.x * 64;

    f32x4 acc[4][2];
#pragma unroll
    for (int m = 0; m < 4; ++m)
#pragma unroll
        for (int n = 0; n < 2; ++n) acc[m][n] = (f32x4){0.f, 0.f, 0.f, 0.f};

    short* As = (short*)smem_raw;             // [128][64]
    short* Bs = (short*)(smem_raw + 16384);   // [64][64]

    for (int kt = 0; kt < 16; ++kt) {
#pragma unroll
        for (int i = 0; i < 4; ++i) {
            int c = tid + 256 * i;
            int r = c >> 3, gs = (c & 7) ^ (r & 7);
            gload_lds16((const char*)A + (size_t)(row0 + r) * 2048 + (size_t)kt * 128 + gs * 16, As + c * 8);
        }
#pragma unroll
        for (int i = 0; i < 2; ++i) {
            int c = tid + 256 * i;
            int r = c >> 3, gs = (c & 7) ^ (r & 7);
            gload_lds16((const char*)Bw + (size_t)(col0 + r) * 2048 + (size_t)kt * 128 + gs * 16, Bs + c * 8);
        }
        __syncthreads();
        bf16x8 af0[4], af1[4], bf0[2], bf1[2];
#pragma unroll
        for (int m = 0; m < 4; ++m) {
            int rl = wr * 64 + m * 16 + lm, rb = rl & 7;
            af0[m] = *(const bf16x8*)&As[rl * 64 + ((lg ^ rb) << 3)];
            af1[m] = *(const bf16x8*)&As[rl * 64 + (((lg + 4) ^ rb) << 3)];
        }
#pragma unroll
        for (int n = 0; n < 2; ++n) {
            int rl = wc * 32 + n * 16 + lm, rb = rl & 7;
            bf0[n] = *(const bf16x8*)&Bs[rl * 64 + ((lg ^ rb) << 3)];
            bf1[n] = *(const bf16x8*)&Bs[rl * 64 + (((lg + 4) ^ rb) << 3)];
        }
#pragma unroll
        for (int m = 0; m < 4; ++m)
#pragma unroll
            for (int n = 0; n < 2; ++n) {
                acc[m][n] = MFMA16(af0[m], bf0[n], acc[m][n]);
                acc[m][n] = MFMA16(af1[m], bf1[n], acc[m][n]);
            }
        __syncthreads();
    }

#pragma unroll
    for (int m = 0; m < 4; ++m) {
        int row = row0 + wr * 64 + m * 16 + lg * 4;
#pragma unroll
        for (int n = 0; n < 2; ++n) {
            int col = col0 + wc * 32 + n * 16 + lm;
            float bv = bias[col];
#pragma unroll
            for (int r = 0; r < 4; ++r)
                Cout[(size_t)(row + r) * DIM + col] = acc[m][n][r] + bv;
        }
    }
}

// ---------- sliding-window flash attention: QBLK=64, KVBLK=128 ----------
// T14 async-STAGE split: K/V reg-staged (8 x uint4/thread); loads for tile t+1 issued
// BEFORE computing tile t -> HBM/L2 latency hides under QK+SM+PV. Same source addresses
// and linear LDS slots as the gload_lds version (byte-identical LDS contents).
__global__ __launch_bounds__(256, 4) void attn(const unsigned short* __restrict__ qb,
                                               const unsigned short* __restrict__ kb,
                                               const unsigned short* __restrict__ vt,
                                               unsigned short* __restrict__ ao) {
    const int p = blockIdx.x;
    const int L = (p & 7) * 128 + (p >> 3);    // bijective: 1024 = 8*128
    const int qblk = L & 31, bh = L >> 5;
    const int b = bh >> 4, h = bh & 15;
    const int tid = threadIdx.x, w = tid >> 6, lane = tid & 63;
    const int lm = lane & 15, lg = lane >> 4;
    const unsigned short* Qb = qb + (size_t)bh * S_LEN * 64;
    const unsigned short* Kb = kb + (size_t)bh * S_LEN * 64;
    const unsigned short* Vt = vt + (size_t)bh * 64 * S_LEN;
    const int q0 = qblk * 64 + w * 16;

    __shared__ short Ks[128 * 64];       // 16KB [k128][d64] granule-swizzled
    __shared__ short Vs[64 * 128];       // 16KB [d64][s128] granule-swizzled
    __shared__ short Plds[4][16 * 64];   // 8KB  per-wave
    short* Pw = Plds[w];

    bf16x8 aq0 = *(const bf16x8*)&Qb[(q0 + lm) * 64 + lg * 8];
    bf16x8 aq1 = *(const bf16x8*)&Qb[(q0 + lm) * 64 + lg * 8 + 32];

    f32x4 o[4];
#pragma unroll
    for (int n = 0; n < 4; ++n) o[n] = (f32x4){0.f, 0.f, 0.f, 0.f};
    float lsum = 0.f;

    const int qq = q0 + lm;
    const int t0_64 = qblk >= 8 ? qblk - 8 : 0;
    const int first = t0_64 >> 1, last = qblk >> 1;
    const int sw = lm & 7;

    uint4 kr[4], vr[4];
    auto loadKV = [&](int kt) {
#pragma unroll
        for (int i = 0; i < 4; ++i) {
            int c = tid + 256 * i;
            int r = c >> 3, g = (c & 7) ^ (r & 7);
            kr[i] = *(const uint4*)(Kb + (size_t)(kt * 128 + r) * 64 + g * 8);
        }
#pragma unroll
        for (int i = 0; i < 4; ++i) {
            int c = tid + 256 * i;
            int r = c >> 4, g = (c & 15) ^ (r & 7);
            vr[i] = *(const uint4*)(Vt + (size_t)r * S_LEN + kt * 128 + g * 8);
        }
    };

    loadKV(first);
    for (int kt = first; kt <= last; ++kt) {
        __syncthreads();                 // all waves done reading previous tile
#pragma unroll
        for (int i = 0; i < 4; ++i) { int c = tid + 256 * i; *(uint4*)&Ks[c * 8] = kr[i]; }
#pragma unroll
        for (int i = 0; i < 4; ++i) { int c = tid + 256 * i; *(uint4*)&Vs[c * 8] = vr[i]; }
        __syncthreads();                 // tile kt ready in LDS
        if (kt < last) loadKV(kt + 1);   // issue early: flies under the compute below
#pragma unroll
        for (int half = 0; half < 2; ++half) {
            const int h64 = kt * 2 + half;
            if (h64 < t0_64 || h64 > qblk) continue;
            const int kbase = h64 * 64;
            f32x4 sT[4];
            __builtin_amdgcn_s_setprio(1);
#pragma unroll
            for (int n = 0; n < 4; ++n) {
                int rl = half * 64 + n * 16 + lm;        // rl&7 == sw
                bf16x8 bk0 = *(const bf16x8*)&Ks[rl * 64 + ((lg ^ sw) << 3)];
                bf16x8 bk1 = *(const bf16x8*)&Ks[rl * 64 + (((lg + 4) ^ sw) << 3)];
                f32x4 z = (f32x4){0.f, 0.f, 0.f, 0.f};
                z = MFMA16(bk0, aq0, z);
                sT[n] = MFMA16(bk1, aq1, z);
            }
            __builtin_amdgcn_s_setprio(0);
#pragma unroll
            for (int n = 0; n < 4; ++n) {
                int kk0 = kbase + n * 16 + lg * 4;
#pragma unroll
                for (int r = 0; r < 4; ++r) {
                    int d = qq - (kk0 + r);
                    float pv = ((unsigned)d < (unsigned)WIN) ? __expf(sT[n][r]) : 0.f;
                    sT[n][r] = pv;
                    lsum += pv;
                }
                uint2 pk;
                pk.x = pack2bf(sT[n][0], sT[n][1]);
                pk.y = pack2bf(sT[n][2], sT[n][3]);
                *(uint2*)&Pw[lm * 64 + ((((2 * n + (lg >> 1)) ^ sw) << 3) + ((lg & 1) << 2))] = pk;
            }
            bf16x8 ap0 = *(const bf16x8*)&Pw[lm * 64 + ((lg ^ sw) << 3)];
            bf16x8 ap1 = *(const bf16x8*)&Pw[lm * 64 + (((lg + 4) ^ sw) << 3)];
            __builtin_amdgcn_s_setprio(1);
#pragma unroll
            for (int n = 0; n < 4; ++n) {
                int rl = n * 16 + lm;
                bf16x8 bv0 = *(const bf16x8*)&Vs[rl * 128 + half * 64 + ((lg ^ sw) << 3)];
                bf16x8 bv1 = *(const bf16x8*)&Vs[rl * 128 + half * 64 + (((lg + 4) ^ sw) << 3)];
                o[n] = MFMA16(ap0, bv0, o[n]);
                o[n] = MFMA16(ap1, bv1, o[n]);
            }
            __builtin_amdgcn_s_setprio(0);
        }
    }
    lsum += __shfl_xor(lsum, 16, 64);
    lsum += __shfl_xor(lsum, 32, 64);
    float linv = 1.f / lsum;
    float lrow[4];
#pragma unroll
    for (int r = 0; r < 4; ++r) lrow[r] = __shfl(linv, lg * 4 + r, 64);
#pragma unroll
    for (int n = 0; n < 4; ++n)
#pragma unroll
        for (int r = 0; r < 4; ++r) {
            int row = b * S_LEN + q0 + lg * 4 + r;
            int col = h * 64 + n * 16 + lm;
            ao[(size_t)row * DIM + col] = f2bf(o[n][r] * lrow[r]);
        }
}

// ---------- launch ----------
extern "C" void kernel_launch(void* const* d_in, const int* in_sizes, int n_in,
                              void* d_out, int out_size, void* d_ws, size_t ws_size,
                              hipStream_t stream) {
    const float* x      = (const float*)d_in[0];
    const float* qkv_w  = (const float*)d_in[1];
    const float* qkv_b  = (const float*)d_in[2];
    const float* out_w  = (const float*)d_in[3];
    const float* out_b  = (const float*)d_in[4];
    (void)in_sizes; (void)n_in; (void)out_size; (void)ws_size;

    char* ws = (char*)d_ws;
    float*          cosT = (float*)(ws + 0);
    float*          sinT = (float*)(ws + 262144);
    unsigned short* xb   = (unsigned short*)(ws + 524288);
    unsigned short* wqb  = (unsigned short*)(ws + 8912896);
    unsigned short* owb  = (unsigned short*)(ws + 15204352);
    unsigned short* qbuf = (unsigned short*)(ws + 17301504);
    unsigned short* kbuf = (unsigned short*)(ws + 25690112);
    unsigned short* vtb  = (unsigned short*)(ws + 34078720);
    unsigned short* aob  = (unsigned short*)(ws + 42467328);

    prep<<<8448, 256, 0, stream>>>(cosT, sinT, x, xb, qkv_w, wqb, out_w, owb);

    // by on the FAST grid axis (x): 16%8==0 partitions A-rows cleanly across XCDs
    gemm_qkv8<<<dim3(16, 12), 512, 0, stream>>>(xb, wqb, qkv_b, cosT, sinT,
                                                qbuf, kbuf, vtb);

    attn<<<1024, 256, 0, stream>>>(qbuf, kbuf, vtb, aob);

    gemm_out<<<dim3(16, 32), 256, 0, stream>>>(aob, owb, out_b, (float*)d_out);
}

// Round 17
// 92.290 us; speedup vs baseline: 1.3136x; 1.3136x over previous
//
#include <hip/hip_runtime.h>
#include <hip/hip_bf16.h>
#include <cstdint>
#include <cstddef>

// ---------- types ----------
using bf16x8 = __attribute__((ext_vector_type(8))) short;
using f32x4  = __attribute__((ext_vector_type(4))) float;

#define MFMA16(a, b, c) __builtin_amdgcn_mfma_f32_16x16x32_bf16((a), (b), (c), 0, 0, 0)

__device__ __forceinline__ unsigned short f2bf(float f) {
    unsigned int u = __float_as_uint(f);
    u += 0x7fffu + ((u >> 16) & 1u);   // round-to-nearest-even
    return (unsigned short)(u >> 16);
}
__device__ __forceinline__ uint32_t pack2bf(float a, float b) {
    __hip_bfloat162 h = __float22bfloat162_rn(float2{a, b});
    return *(uint32_t*)&h;
}
__device__ __forceinline__ float bf2f(short x) {
    return __uint_as_float(((uint32_t)(unsigned short)x) << 16);
}

__device__ __forceinline__ void gload_lds16(const void* g, void* l) {
    __builtin_amdgcn_global_load_lds(
        (const __attribute__((address_space(1))) void*)g,
        (__attribute__((address_space(3))) void*)l, 16, 0, 0);
}

// ---------- constants ----------
#define S_LEN 2048
#define NHEAD 16
#define HDIM  64
#define DIM   1024
#define WIN   512
#define MROWS 4096            // B*S

// ---------- kernel 0 (fused prep): rope table + 3 bf16 casts ----------
__global__ void prep(float* __restrict__ cosT, float* __restrict__ sinT,
                     const float* __restrict__ x, unsigned short* __restrict__ xb,
                     const float* __restrict__ qw, unsigned short* __restrict__ qwb,
                     const float* __restrict__ ow, unsigned short* __restrict__ owb) {
    int t = blockIdx.x * 256 + threadIdx.x;
    if (t < 65536) {
        int s = t >> 5, f = t & 31;
        float invf = powf(10000.0f, -(float)f / 32.0f);
        float ang = (float)s * invf;
        cosT[t] = cosf(ang);
        sinT[t] = sinf(ang);
        return;
    }
    int u = t - 65536;
    const float* src;
    unsigned short* dst;
    int i;
    if (u < 1048576)        { src = x;  dst = xb;  i = u * 4; }
    else if (u < 1835008)   { src = qw; dst = qwb; i = (u - 1048576) * 4; }
    else                    { src = ow; dst = owb; i = (u - 1835008) * 4; }
    float4 v = *(const float4*)(src + i);
    ushort4 o;
    o.x = f2bf(v.x); o.y = f2bf(v.y); o.z = f2bf(v.z); o.w = f2bf(v.w);
    *(ushort4*)(dst + i) = o;
}

// ---------- fused QKV GEMM: 256x256 tile, 8-phase counted-vmcnt schedule (R11-proven) ----------
// Grid (16 by-fast, 12 bx): 16%8==0 -> all 12 blocks sharing an A-row-tile land on ONE XCD
// (A L2-resident; R14 counter-proof: FETCH 47.0 -> 35.5MB).
__global__ __launch_bounds__(512, 2) void gemm_qkv8(
        const unsigned short* __restrict__ A,    // xb   [4096][1024]
        const unsigned short* __restrict__ Bw,   // wqb  [3072][1024]
        const float* __restrict__ bias,          // qkv_b[3072]
        const float* __restrict__ cosT, const float* __restrict__ sinT,
        unsigned short* __restrict__ qbuf,       // [32][2048][64]
        unsigned short* __restrict__ kbuf,       // [32][2048][64]
        unsigned short* __restrict__ vtb) {      // [32][64][2048]
    __shared__ __align__(16) char smem[131072];
    const int tid = threadIdx.x;
    const int lane = tid & 63, w = tid >> 6;
    const int wr = w >> 2, wn = w & 3;           // M-half, N-quarter
    const int lm = lane & 15, lg = lane >> 4;
    const int bx = blockIdx.y, by = blockIdx.x;  // by = fast axis
    const int row0 = by * 256, col0 = bx * 256;

    f32x4 acc[8][4];
#pragma unroll
    for (int mf = 0; mf < 8; ++mf)
#pragma unroll
        for (int nf = 0; nf < 4; ++nf) acc[mf][nf] = (f32x4){0.f, 0.f, 0.f, 0.f};

    short* SA0 = (short*)smem;                   // buf0 A (32KB)
    short* SB0 = (short*)(smem + 32768);         // buf0 B
    short* SA1 = (short*)(smem + 65536);         // buf1 A
    short* SB1 = (short*)(smem + 98304);         // buf1 B

    auto stageA = [&](int t) {
        int tt = t & 15;                          // wrap keeps parity; dummies harmless
        short* dst = (tt & 1) ? SA1 : SA0;
#pragma unroll
        for (int j = 0; j < 4; ++j) {
            int slot = tid + 512 * j;             // 2048 x 16B = 32KB
            int r = slot >> 3, gp = slot & 7, gs = gp ^ (r & 7);
            gload_lds16((const char*)A + (size_t)(row0 + r) * 2048 + tt * 128 + gs * 16,
                        dst + slot * 8);
        }
    };
    auto stageB = [&](int t) {
        int tt = t & 15;
        short* dst = (tt & 1) ? SB1 : SB0;
#pragma unroll
        for (int j = 0; j < 4; ++j) {
            int slot = tid + 512 * j;
            int r = slot >> 3, gp = slot & 7, gs = gp ^ (r & 7);
            gload_lds16((const char*)Bw + (size_t)(col0 + r) * 2048 + tt * 128 + gs * 16,
                        dst + slot * 8);
        }
    };

    // prologue: A(0) B(0) B(1) -> 12 outstanding; Ph1's vmcnt(4) waits oldest 8 (t0 A+B)
    stageA(0); stageB(0); stageB(1);

    const int rA = wr * 128;                     // wave A-row base
    const int rB = wn * 64;                      // wave B-row base

    for (int i = 0; i < 8; ++i) {
        const int u = 2 * i, v = 2 * i + 1;
        bf16x8 a[8], bq[4][2];
        // ---- Ph1: read u(kh0 A, both-kh B) from buf0; stage A(v)->buf1A; MFMA u,kh0
        asm volatile("s_waitcnt vmcnt(4)" ::: "memory");
        __builtin_amdgcn_s_barrier();
#pragma unroll
        for (int mf = 0; mf < 8; ++mf) {
            int r = rA + mf * 16 + lm;
            a[mf] = *(const bf16x8*)&SA0[r * 64 + ((lg ^ (r & 7)) << 3)];
        }
#pragma unroll
        for (int nf = 0; nf < 4; ++nf) {
            int r = rB + nf * 16 + lm;
            bq[nf][0] = *(const bf16x8*)&SB0[r * 64 + ((lg ^ (r & 7)) << 3)];
            bq[nf][1] = *(const bf16x8*)&SB0[r * 64 + (((lg + 4) ^ (r & 7)) << 3)];
        }
        stageA(v);
        __builtin_amdgcn_s_setprio(1);
#pragma unroll
        for (int mf = 0; mf < 8; ++mf)
#pragma unroll
            for (int nf = 0; nf < 4; ++nf)
                acc[mf][nf] = MFMA16(a[mf], bq[nf][0], acc[mf][nf]);
        __builtin_amdgcn_s_setprio(0);
        // ---- Ph2: read u kh1 A; stage B(u+2)->buf0B; MFMA u,kh1
        __builtin_amdgcn_s_barrier();
#pragma unroll
        for (int mf = 0; mf < 8; ++mf) {
            int r = rA + mf * 16 + lm;
            a[mf] = *(const bf16x8*)&SA0[r * 64 + (((lg + 4) ^ (r & 7)) << 3)];
        }
        stageB(u + 2);
        __builtin_amdgcn_s_setprio(1);
#pragma unroll
        for (int mf = 0; mf < 8; ++mf)
#pragma unroll
            for (int nf = 0; nf < 4; ++nf)
                acc[mf][nf] = MFMA16(a[mf], bq[nf][1], acc[mf][nf]);
        __builtin_amdgcn_s_setprio(0);
        // ---- Ph3: read v(kh0 A, both-kh B) from buf1; stage A(u+2)->buf0A; MFMA v,kh0
        asm volatile("s_waitcnt vmcnt(4)" ::: "memory");
        __builtin_amdgcn_s_barrier();
#pragma unroll
        for (int mf = 0; mf < 8; ++mf) {
            int r = rA + mf * 16 + lm;
            a[mf] = *(const bf16x8*)&SA1[r * 64 + ((lg ^ (r & 7)) << 3)];
        }
#pragma unroll
        for (int nf = 0; nf < 4; ++nf) {
            int r = rB + nf * 16 + lm;
            bq[nf][0] = *(const bf16x8*)&SB1[r * 64 + ((lg ^ (r & 7)) << 3)];
            bq[nf][1] = *(const bf16x8*)&SB1[r * 64 + (((lg + 4) ^ (r & 7)) << 3)];
        }
        stageA(u + 2);
        __builtin_amdgcn_s_setprio(1);
#pragma unroll
        for (int mf = 0; mf < 8; ++mf)
#pragma unroll
            for (int nf = 0; nf < 4; ++nf)
                acc[mf][nf] = MFMA16(a[mf], bq[nf][0], acc[mf][nf]);
        __builtin_amdgcn_s_setprio(0);
        // ---- Ph4: read v kh1 A; stage B(v+2)->buf1B; MFMA v,kh1
        __builtin_amdgcn_s_barrier();
#pragma unroll
        for (int mf = 0; mf < 8; ++mf) {
            int r = rA + mf * 16 + lm;
            a[mf] = *(const bf16x8*)&SA1[r * 64 + (((lg + 4) ^ (r & 7)) << 3)];
        }
        stageB(v + 2);
        __builtin_amdgcn_s_setprio(1);
#pragma unroll
        for (int mf = 0; mf < 8; ++mf)
#pragma unroll
            for (int nf = 0; nf < 4; ++nf)
                acc[mf][nf] = MFMA16(a[mf], bq[nf][1], acc[mf][nf]);
        __builtin_amdgcn_s_setprio(0);
    }
    // drain dummy stages before LDS overlay reuse
    asm volatile("s_waitcnt vmcnt(0)" ::: "memory");
    __builtin_amdgcn_s_barrier();

    // ---------- fused epilogue: bias + (RoPE pack | V transpose), 2 passes of 128 rows ----------
    const int plane = bx >> 2;                   // 0=Q 1=K 2=V
    const int h0 = (bx & 3) * 4;                 // 4 heads per 256-col tile
    const int b = by >> 3, s_base = (by & 7) * 256;
    const int lane8 = tid & 7, idx = tid >> 3;   // idx 0..63

#pragma unroll 1
    for (int p = 0; p < 2; ++p) {
        if (plane < 2) {
            unsigned short (*tile)[264] = (unsigned short(*)[264])smem;  // [128][256+8]
            if (wr == p) {
#pragma unroll
                for (int mf = 0; mf < 8; ++mf)
#pragma unroll
                    for (int nf = 0; nf < 4; ++nf) {
                        int colL = wn * 64 + nf * 16 + lm;
                        float bv = bias[col0 + colL];
#pragma unroll
                        for (int r = 0; r < 4; ++r)
                            tile[mf * 16 + lg * 4 + r][colL] = f2bf(acc[mf][nf][r] + bv);
                    }
            }
            __syncthreads();
            unsigned short* dstp = (plane == 0) ? qbuf : kbuf;
            const float qsc = (plane == 0) ? 0.125f : 1.0f;
            int d0 = lane8 * 8;
#pragma unroll
            for (int j = 0; j < 2; ++j) {
                int rloc = idx + 64 * j;                     // 0..127
                int s = s_base + p * 128 + rloc;
                float4 c4 = *(const float4*)&cosT[s * 32 + (d0 >> 1)];
                float4 s4 = *(const float4*)&sinT[s * 32 + (d0 >> 1)];
#pragma unroll
                for (int hh = 0; hh < 4; ++hh) {
                    bf16x8 vld = *(const bf16x8*)&tile[rloc][hh * 64 + d0];
                    float e0 = bf2f(vld[0]), o0 = bf2f(vld[1]);
                    float e1 = bf2f(vld[2]), o1 = bf2f(vld[3]);
                    float e2 = bf2f(vld[4]), o2 = bf2f(vld[5]);
                    float e3 = bf2f(vld[6]), o3 = bf2f(vld[7]);
                    uint4 pk;
                    pk.x = pack2bf((e0 * c4.x - o0 * s4.x) * qsc, (e0 * s4.x + o0 * c4.x) * qsc);
                    pk.y = pack2bf((e1 * c4.y - o1 * s4.y) * qsc, (e1 * s4.y + o1 * c4.y) * qsc);
                    pk.z = pack2bf((e2 * c4.z - o2 * s4.z) * qsc, (e2 * s4.z + o2 * c4.z) * qsc);
                    pk.w = pack2bf((e3 * c4.w - o3 * s4.w) * qsc, (e3 * s4.w + o3 * c4.w) * qsc);
                    int h = h0 + hh;
                    *(uint4*)&dstp[(((size_t)(b * NHEAD + h)) * S_LEN + s) * 64 + d0] = pk;
                }
            }
            __syncthreads();
        } else {
            unsigned short (*tileT)[136] = (unsigned short(*)[136])smem;  // [256][128+8]
            if (wr == p) {
#pragma unroll
                for (int mf = 0; mf < 8; ++mf)
#pragma unroll
                    for (int nf = 0; nf < 4; ++nf) {
                        int colL = wn * 64 + nf * 16 + lm;
                        float bv = bias[col0 + colL];
                        uint2 pk;
                        pk.x = pack2bf(acc[mf][nf][0] + bv, acc[mf][nf][1] + bv);
                        pk.y = pack2bf(acc[mf][nf][2] + bv, acc[mf][nf][3] + bv);
                        *(uint2*)&tileT[colL][mf * 16 + lg * 4] = pk;
                    }
            }
            __syncthreads();
#pragma unroll
            for (int ff = 0; ff < 4; ++ff) {
                int f = ff * 64 + idx;                       // feature 0..255
                int hh = f >> 6, d = f & 63, h = h0 + hh;
#pragma unroll
                for (int j = 0; j < 2; ++j) {
                    int s0 = lane8 * 8 + j * 64;             // 0..127
                    bf16x8 vld = *(const bf16x8*)&tileT[f][s0];
                    *(bf16x8*)&vtb[((size_t)(b * NHEAD + h) * 64 + d) * S_LEN +
                                   s_base + p * 128 + s0] = vld;
                }
            }
            __syncthreads();
        }
    }
}

// ---------- out-proj GEMM: 128x64 tile, BK=64, single buffer, fp32 out ----------
__global__ __launch_bounds__(256) void gemm_out(const unsigned short* __restrict__ A,
                                                const unsigned short* __restrict__ Bw,
                                                const float* __restrict__ bias,
                                                float* __restrict__ Cout) {
    __shared__ __align__(16) char smem_raw[24576];  // A [128][64] 16KB + B [64][64] 8KB
    const int tid = threadIdx.x;
    const int lane = tid & 63, w = tid >> 6;
    const int wr = w >> 1, wc = w & 1, lm = lane & 15, lg = lane >> 4;
    const int row0 = blockIdx.y * 128, col0 = blockIdx.x * 64;

    f32x4 acc[4][2];
#pragma unroll
    for (int m = 0; m < 4; ++m)
#pragma unroll
        for (int n = 0; n < 2; ++n) acc[m][n] = (f32x4){0.f, 0.f, 0.f, 0.f};

    short* As = (short*)smem_raw;             // [128][64]
    short* Bs = (short*)(smem_raw + 16384);   // [64][64]

    for (int kt = 0; kt < 16; ++kt) {
#pragma unroll
        for (int i = 0; i < 4; ++i) {
            int c = tid + 256 * i;
            int r = c >> 3, gs = (c & 7) ^ (r & 7);
            gload_lds16((const char*)A + (size_t)(row0 + r) * 2048 + (size_t)kt * 128 + gs * 16, As + c * 8);
        }
#pragma unroll
        for (int i = 0; i < 2; ++i) {
            int c = tid + 256 * i;
            int r = c >> 3, gs = (c & 7) ^ (r & 7);
            gload_lds16((const char*)Bw + (size_t)(col0 + r) * 2048 + (size_t)kt * 128 + gs * 16, Bs + c * 8);
        }
        __syncthreads();
        bf16x8 af0[4], af1[4], bf0[2], bf1[2];
#pragma unroll
        for (int m = 0; m < 4; ++m) {
            int rl = wr * 64 + m * 16 + lm, rb = rl & 7;
            af0[m] = *(const bf16x8*)&As[rl * 64 + ((lg ^ rb) << 3)];
            af1[m] = *(const bf16x8*)&As[rl * 64 + (((lg + 4) ^ rb) << 3)];
        }
#pragma unroll
        for (int n = 0; n < 2; ++n) {
            int rl = wc * 32 + n * 16 + lm, rb = rl & 7;
            bf0[n] = *(const bf16x8*)&Bs[rl * 64 + ((lg ^ rb) << 3)];
            bf1[n] = *(const bf16x8*)&Bs[rl * 64 + (((lg + 4) ^ rb) << 3)];
        }
#pragma unroll
        for (int m = 0; m < 4; ++m)
#pragma unroll
            for (int n = 0; n < 2; ++n) {
                acc[m][n] = MFMA16(af0[m], bf0[n], acc[m][n]);
                acc[m][n] = MFMA16(af1[m], bf1[n], acc[m][n]);
            }
        __syncthreads();
    }

#pragma unroll
    for (int m = 0; m < 4; ++m) {
        int row = row0 + wr * 64 + m * 16 + lg * 4;
#pragma unroll
        for (int n = 0; n < 2; ++n) {
            int col = col0 + wc * 32 + n * 16 + lm;
            float bv = bias[col];
#pragma unroll
            for (int r = 0; r < 4; ++r)
                Cout[(size_t)(row + r) * DIM + col] = acc[m][n][r] + bv;
        }
    }
}

// ---------- sliding-window flash attention: QBLK=64, KVBLK=128, single LDS buffer ----------
// R8/R10-proven version: global_load_lds staging (R15's reg-staging spilled to scratch:
// WRITE_SIZE 8MB -> 129MB, attn 24 -> 61us; reverted).
__global__ __launch_bounds__(256) void attn(const unsigned short* __restrict__ qb,
                                            const unsigned short* __restrict__ kb,
                                            const unsigned short* __restrict__ vt,
                                            unsigned short* __restrict__ ao) {
    const int p = blockIdx.x;
    const int L = (p & 7) * 128 + (p >> 3);    // bijective: 1024 = 8*128
    const int qblk = L & 31, bh = L >> 5;
    const int b = bh >> 4, h = bh & 15;
    const int tid = threadIdx.x, w = tid >> 6, lane = tid & 63;
    const int lm = lane & 15, lg = lane >> 4;
    const unsigned short* Qb = qb + (size_t)bh * S_LEN * 64;
    const unsigned short* Kb = kb + (size_t)bh * S_LEN * 64;
    const unsigned short* Vt = vt + (size_t)bh * 64 * S_LEN;
    const int q0 = qblk * 64 + w * 16;

    __shared__ short Ks[128 * 64];       // 16KB [k128][d64] granule-swizzled
    __shared__ short Vs[64 * 128];       // 16KB [d64][s128] granule-swizzled
    __shared__ short Plds[4][16 * 64];   // 8KB  per-wave
    short* Pw = Plds[w];

    bf16x8 aq0 = *(const bf16x8*)&Qb[(q0 + lm) * 64 + lg * 8];
    bf16x8 aq1 = *(const bf16x8*)&Qb[(q0 + lm) * 64 + lg * 8 + 32];

    f32x4 o[4];
#pragma unroll
    for (int n = 0; n < 4; ++n) o[n] = (f32x4){0.f, 0.f, 0.f, 0.f};
    float lsum = 0.f;

    const int qq = q0 + lm;
    const int t0_64 = qblk >= 8 ? qblk - 8 : 0;
    const int first = t0_64 >> 1, last = qblk >> 1;
    const int sw = lm & 7;

    for (int kt = first; kt <= last; ++kt) {
#pragma unroll
        for (int i = 0; i < 4; ++i) {
            int c = tid + 256 * i;
            int r = c >> 3, g = (c & 7) ^ (r & 7);
            gload_lds16(Kb + (size_t)(kt * 128 + r) * 64 + g * 8, &Ks[c * 8]);
        }
#pragma unroll
        for (int i = 0; i < 4; ++i) {
            int c = tid + 256 * i;
            int r = c >> 4, g = (c & 15) ^ (r & 7);
            gload_lds16(Vt + (size_t)r * S_LEN + kt * 128 + g * 8, &Vs[c * 8]);
        }
        __syncthreads();
#pragma unroll
        for (int half = 0; half < 2; ++half) {
            const int h64 = kt * 2 + half;
            if (h64 < t0_64 || h64 > qblk) continue;
            const int kbase = h64 * 64;
            f32x4 sT[4];
            __builtin_amdgcn_s_setprio(1);
#pragma unroll
            for (int n = 0; n < 4; ++n) {
                int rl = half * 64 + n * 16 + lm;        // rl&7 == sw
                bf16x8 bk0 = *(const bf16x8*)&Ks[rl * 64 + ((lg ^ sw) << 3)];
                bf16x8 bk1 = *(const bf16x8*)&Ks[rl * 64 + (((lg + 4) ^ sw) << 3)];
                f32x4 z = (f32x4){0.f, 0.f, 0.f, 0.f};
                z = MFMA16(bk0, aq0, z);
                sT[n] = MFMA16(bk1, aq1, z);
            }
            __builtin_amdgcn_s_setprio(0);
#pragma unroll
            for (int n = 0; n < 4; ++n) {
                int kk0 = kbase + n * 16 + lg * 4;
#pragma unroll
                for (int r = 0; r < 4; ++r) {
                    int d = qq - (kk0 + r);
                    float pv = ((unsigned)d < (unsigned)WIN) ? __expf(sT[n][r]) : 0.f;
                    sT[n][r] = pv;
                    lsum += pv;
                }
                uint2 pk;
                pk.x = pack2bf(sT[n][0], sT[n][1]);
                pk.y = pack2bf(sT[n][2], sT[n][3]);
                *(uint2*)&Pw[lm * 64 + ((((2 * n + (lg >> 1)) ^ sw) << 3) + ((lg & 1) << 2))] = pk;
            }
            bf16x8 ap0 = *(const bf16x8*)&Pw[lm * 64 + ((lg ^ sw) << 3)];
            bf16x8 ap1 = *(const bf16x8*)&Pw[lm * 64 + (((lg + 4) ^ sw) << 3)];
            __builtin_amdgcn_s_setprio(1);
#pragma unroll
            for (int n = 0; n < 4; ++n) {
                int rl = n * 16 + lm;
                bf16x8 bv0 = *(const bf16x8*)&Vs[rl * 128 + half * 64 + ((lg ^ sw) << 3)];
                bf16x8 bv1 = *(const bf16x8*)&Vs[rl * 128 + half * 64 + (((lg + 4) ^ sw) << 3)];
                o[n] = MFMA16(ap0, bv0, o[n]);
                o[n] = MFMA16(ap1, bv1, o[n]);
            }
            __builtin_amdgcn_s_setprio(0);
        }
        __syncthreads();
    }
    lsum += __shfl_xor(lsum, 16, 64);
    lsum += __shfl_xor(lsum, 32, 64);
    float linv = 1.f / lsum;
    float lrow[4];
#pragma unroll
    for (int r = 0; r < 4; ++r) lrow[r] = __shfl(linv, lg * 4 + r, 64);
#pragma unroll
    for (int n = 0; n < 4; ++n)
#pragma unroll
        for (int r = 0; r < 4; ++r) {
            int row = b * S_LEN + q0 + lg * 4 + r;
            int col = h * 64 + n * 16 + lm;
            ao[(size_t)row * DIM + col] = f2bf(o[n][r] * lrow[r]);
        }
}

// ---------- launch ----------
extern "C" void kernel_launch(void* const* d_in, const int* in_sizes, int n_in,
                              void* d_out, int out_size, void* d_ws, size_t ws_size,
                              hipStream_t stream) {
    const float* x      = (const float*)d_in[0];
    const float* qkv_w  = (const float*)d_in[1];
    const float* qkv_b  = (const float*)d_in[2];
    const float* out_w  = (const float*)d_in[3];
    const float* out_b  = (const float*)d_in[4];
    (void)in_sizes; (void)n_in; (void)out_size; (void)ws_size;

    char* ws = (char*)d_ws;
    float*          cosT = (float*)(ws + 0);
    float*          sinT = (float*)(ws + 262144);
    unsigned short* xb   = (unsigned short*)(ws + 524288);
    unsigned short* wqb  = (unsigned short*)(ws + 8912896);
    unsigned short* owb  = (unsigned short*)(ws + 15204352);
    unsigned short* qbuf = (unsigned short*)(ws + 17301504);
    unsigned short* kbuf = (unsigned short*)(ws + 25690112);
    unsigned short* vtb  = (unsigned short*)(ws + 34078720);
    unsigned short* aob  = (unsigned short*)(ws + 42467328);

    prep<<<8448, 256, 0, stream>>>(cosT, sinT, x, xb, qkv_w, wqb, out_w, owb);

    // by on the FAST grid axis (x): 16%8==0 partitions A-rows cleanly across XCDs
    gemm_qkv8<<<dim3(16, 12), 512, 0, stream>>>(xb, wqb, qkv_b, cosT, sinT,
                                                qbuf, kbuf, vtb);

    attn<<<1024, 256, 0, stream>>>(qbuf, kbuf, vtb, aob);

    gemm_out<<<dim3(16, 32), 256, 0, stream>>>(aob, owb, out_b, (float*)d_out);
}